// Round 8
// baseline (636.920 us; speedup 1.0000x reference)
//
#include <hip/hip_runtime.h>

// Encoder_8718783611479: stateless per-step LSTMCell => one GEMM + elementwise.
//   gates = xt @ W_ih^T (+ b_ih + b_hh), only i,g,o gates live (f * c_prev = 0)
//   out = sigmoid(sigmoid(o_g)*tanh(sigmoid(i_g)*tanh(g_g)))
// xt[b,t,k] = x[b*43200 + k*240 + t]  (K=180 strided, M=t contiguous)
//
// v9: v8 falsified resident-W (pinned 168-reg budget -> allocator still chose
// 72 and remats W from the L2-hot pack; v5 did too — its win was ~24 waves/CU
// occupancy, which v8's (3,3) max-cap clamped to 12). Kernel time == hbm_bytes
// / achieved_BW (390MB @ 1.74TB/s = 224us) while fill proves 6.5TB/s: we are
// HBM duty-cycle bound (serial stage->compute per block). Fix: per-tile
// prefetch pipeline with tiny LDS: aBuf = 2 x [16][192] bf16 (12.3KB),
// issue tile t+1 loads -> compute/epilogue tile t -> transpose+ds_write t+1
// -> lgkm-only barrier (no vmcnt drain: stores + prefetch stay in flight
// across barriers). Per-tile barriers keep the proven store-compactness.
// Swizzle re-derived for 16-row buffers: key(t)=(2t)&14 -> both ds_write_b64
// and ds_read_b128 at bank floor (verified by construction).

#define B_SZ 2048
#define T_SZ 240
#define K_SZ 180
#define H_SZ 90
#define KP   192   // K padded to 6*32
#define TT   16    // t rows per tile / LDS buffer
#define TB   80    // t per block
#define NP   3     // parts per batch
#define NTT  5     // tiles per block

#define WS_B_OFF 110592   // W frags [3][6][6][64]x16B, then [3][96] f32 biases

typedef __bf16 bf16x8 __attribute__((ext_vector_type(8)));
typedef __bf16 bf16x4 __attribute__((ext_vector_type(4)));
typedef float  f32x4  __attribute__((ext_vector_type(4)));

__device__ __forceinline__ float sigmoidf_(float x) {
    return __builtin_amdgcn_rcpf(1.0f + __expf(-x));
}
__device__ __forceinline__ float tanhf_(float x) {
    return 1.0f - 2.0f * __builtin_amdgcn_rcpf(__expf(2.0f * x) + 1.0f);
}

// 16-row-buffer swizzle: granule = 4 bf16 = 8B, key(t) = (2t)&14 (even ->
// preserves even-pair adjacency for b128 reads). Write side (fixed j): 64
// lanes = 16 k4 x 4 t4 -> each bank pair hit 4x = floor. Read side (b128,
// g = ks*8+2q): v = q^(n&7) uniform over 8 four-bank groups = floor.
__device__ __forceinline__ int sg16(int g, int t) {
    return (g & ~15) | ((g ^ ((2 * t) & 14)) & 15);
}

// ---------------- prepack: W fragments + fused bias into d_ws ----------------
__global__ __launch_bounds__(384) void prepack_kernel(
    const float* __restrict__ W_ih,
    const float* __restrict__ b_ih,
    const float* __restrict__ b_hh,
    void* __restrict__ ws)
{
    __bf16* wp = (__bf16*)ws;
    float*  bp = (float*)((char*)ws + WS_B_OFF);
    const int gb[3] = {0, 180, 270};   // i, g, o row bases in W_ih (4H=360 rows)

    const int bid = blockIdx.x;
    const int tid = threadIdx.x;
    if (bid < 18) {
        const int g  = bid / 6;
        const int ks = bid % 6;
        const int w  = tid >> 6;
        const int l  = tid & 63;
        const int q  = l >> 4;
        const int n  = l & 15;
        const int h  = w * 16 + n;
        bf16x8 f;
        #pragma unroll
        for (int j = 0; j < 8; ++j) {
            int k = ks * 32 + q * 8 + j;
            float v = (h < H_SZ && k < K_SZ) ? W_ih[(size_t)(gb[g] + h) * K_SZ + k] : 0.0f;
            f[j] = (__bf16)v;
        }
        // fragment order: [g][ks][wave][lane] x 16B -> coalesced load in main
        *(bf16x8*)(wp + (size_t)(((g * 6 + ks) * 6 + w) * 64 + l) * 8) = f;
    } else {
        if (tid < 288) {
            int g = tid / 96, hh = tid % 96;
            bp[g * 96 + hh] = (hh < H_SZ) ? (b_ih[gb[g] + hh] + b_hh[gb[g] + hh]) : 0.0f;
        }
    }
}

// ---------------- main kernel ----------------
__global__ __launch_bounds__(384, 3) void lstm_fused_kernel(
    const float* __restrict__ x,
    const void*  __restrict__ ws,
    float* __restrict__ out)
{
    __shared__ __align__(16) __bf16 aBuf[2][TT * KP];   // 2 x 6 KB, swizzled

    const int bid  = blockIdx.x;
    const int b    = bid / NP;
    const int part = bid - b * NP;
    const int t0   = part * TB;

    const int tid  = threadIdx.x;
    const int wave = tid >> 6;      // 0..5 -> h-tile
    const int lane = tid & 63;
    const int q    = lane >> 4;     // quad 0..3
    const int n    = lane & 15;
    const int h    = wave * 16 + n; // output column; valid if < 90
    const bool hv  = (h < H_SZ);

    const float* xb = x + (size_t)b * (K_SZ * T_SZ) + t0;

    // staging role: unit = 4 k-rows x 4 t; 45 k4 x 4 t4 = 180 units
    const bool sv = (tid < 180);
    const int  k4 = tid >> 2;
    const int  t4 = tid & 3;

    // zero-fill k-padding granules 45..47 of both buffers (once; data writes
    // never touch them -- XOR swizzle is bijective within 16-granule groups)
    if (tid < 96) {
        int buf = tid / 48;
        int rr  = tid - buf * 48;
        int t   = rr / 3;
        int gz  = 45 + (rr - (rr / 3) * 3);
        *(unsigned long long*)(&aBuf[buf][t * KP + sg16(gz, t) * 4]) = 0ull;
    }

    f32x4 r[4];

    // ---- prologue: stage tile 0 ----
    if (sv) {
        const float* s = xb + (k4 * 4) * T_SZ + t4 * 4;
        #pragma unroll
        for (int j = 0; j < 4; ++j) r[j] = *(const f32x4*)(s + j * T_SZ);
        #pragma unroll
        for (int j = 0; j < 4; ++j) {
            int t = t4 * 4 + j;
            bf16x4 w;
            w[0] = (__bf16)r[0][j]; w[1] = (__bf16)r[1][j];
            w[2] = (__bf16)r[2][j]; w[3] = (__bf16)r[3][j];
            *(bf16x4*)(&aBuf[0][t * KP + sg16(k4, t) * 4]) = w;
        }
    }

    const bf16x8* wp = (const bf16x8*)ws;
    const float*  bp = (const float*)((const char*)ws + WS_B_OFF);
    const float bias_i = bp[0 * 96 + h];   // h <= 95, zero-padded
    const float bias_g = bp[1 * 96 + h];
    const float bias_o = bp[2 * 96 + h];
    float* ob = out + (size_t)b * (T_SZ * H_SZ) + (size_t)t0 * H_SZ;

    __syncthreads();

    int curb = 0;
    #pragma unroll
    for (int m = 0; m < NTT; ++m) {
        // ---- issue next tile's global loads (in flight under compute) ----
        if (m + 1 < NTT && sv) {
            const float* s = xb + (k4 * 4) * T_SZ + (m + 1) * TT + t4 * 4;
            #pragma unroll
            for (int j = 0; j < 4; ++j) r[j] = *(const f32x4*)(s + j * T_SZ);
        }

        // ---- compute tile m from aBuf[curb] ----
        f32x4 acc0 = {0.f, 0.f, 0.f, 0.f};
        f32x4 acc1 = {0.f, 0.f, 0.f, 0.f};
        f32x4 acc2 = {0.f, 0.f, 0.f, 0.f};
        const __bf16* ab = &aBuf[curb][0];
        #pragma unroll
        for (int ks = 0; ks < 6; ++ks) {
            // W fragments: coalesced 16B loads from the L2-hot pack (remat
            // per tile is the measured-best pattern; residency is a myth)
            bf16x8 b0 = wp[((0 * 6 + ks) * 6 + wave) * 64 + lane];
            bf16x8 b1 = wp[((1 * 6 + ks) * 6 + wave) * 64 + lane];
            bf16x8 b2 = wp[((2 * 6 + ks) * 6 + wave) * 64 + lane];
            int g = ks * 8 + 2 * q;            // even granule-pair base
            bf16x8 a = *(const bf16x8*)(ab + n * KP + sg16(g, n) * 4);
            acc0 = __builtin_amdgcn_mfma_f32_16x16x32_bf16(a, b0, acc0, 0, 0, 0);
            acc1 = __builtin_amdgcn_mfma_f32_16x16x32_bf16(a, b1, acc1, 0, 0, 0);
            acc2 = __builtin_amdgcn_mfma_f32_16x16x32_bf16(a, b2, acc2, 0, 0, 0);
        }

        // ---- epilogue tile m (C/D: col=lane&15 -> h, row=q*4+e -> t) ----
        if (hv) {
            const int tg = m * TT + q * 4;
            #pragma unroll
            for (int e = 0; e < 4; ++e) {
                float gi = acc0[e] + bias_i;
                float gg = acc1[e] + bias_g;
                float go = acc2[e] + bias_o;
                float cc = sigmoidf_(gi) * tanhf_(gg);
                float hh = sigmoidf_(go) * tanhf_(cc);
                ob[(size_t)(tg + e) * H_SZ + h] = sigmoidf_(hh);
            }
        }

        // ---- land tile m+1 into the other buffer; lgkm-only barrier ----
        if (m + 1 < NTT) {
            if (sv) {
                __bf16* dst = &aBuf[curb ^ 1][0];
                #pragma unroll
                for (int j = 0; j < 4; ++j) {
                    int t = t4 * 4 + j;
                    bf16x4 w;
                    w[0] = (__bf16)r[0][j]; w[1] = (__bf16)r[1][j];
                    w[2] = (__bf16)r[2][j]; w[3] = (__bf16)r[3][j];
                    *(bf16x4*)(dst + t * KP + sg16(k4, t) * 4) = w;
                }
            }
            // wait own LDS ops only (ds_writes + this tile's ds_reads);
            // epilogue stores and any global loads stay in flight (no vmcnt).
            asm volatile("s_waitcnt lgkmcnt(0)" ::: "memory");
            __builtin_amdgcn_sched_barrier(0);
            __builtin_amdgcn_s_barrier();
            curb ^= 1;
        }
    }
}

extern "C" void kernel_launch(void* const* d_in, const int* in_sizes, int n_in,
                              void* d_out, int out_size, void* d_ws, size_t ws_size,
                              hipStream_t stream) {
    const float* x    = (const float*)d_in[0];
    const float* W_ih = (const float*)d_in[1];
    // d_in[2] = W_hh: dead (h0 = c0 = 0 at every timestep)
    const float* b_ih = (const float*)d_in[3];
    const float* b_hh = (const float*)d_in[4];
    float* out = (float*)d_out;

    // ~112 KB of workspace: prepacked W fragments + fused biases
    prepack_kernel<<<dim3(19), dim3(384), 0, stream>>>(W_ih, b_ih, b_hh, d_ws);
    lstm_fused_kernel<<<dim3(B_SZ * NP), dim3(384), 0, stream>>>(x, d_ws, out);
}